// Round 1
// baseline (3869.046 us; speedup 1.0000x reference)
//
#include <hip/hip_runtime.h>
#include <cstddef>
#include <cstdint>

#define NAU 50000
#define NPA 100000
#define KH 8
#define DH 32
#define KD 256
#define DIN 128
#define SLOPE 0.2f

// ---------------- tiled f32 GEMM (N fixed = 256 cols) ----------------
#define BM 128
#define BN 64
#define BK 16
#define TM 8
#define TN 4
// 256 threads per block, ty=tid/16 (row group), tx=tid%16 (col group)

__device__ __forceinline__ float leakyf(float x) { return x >= 0.f ? x : SLOPE * x; }

template<bool RELU>
__device__ __forceinline__ void gemm_tile_acc(
    float acc[TM][TN],
    const float* __restrict__ A, int M, int Kdim,
    const float* __restrict__ B,   // Kdim x 256 row-major
    int row0, int col0, int tid,
    float (*As)[BM + 4], float (*Bs)[BN])
{
  const int ty = tid >> 4, tx = tid & 15;
  for (int k0 = 0; k0 < Kdim; k0 += BK) {
    __syncthreads();
    // stage A: BM x BK
#pragma unroll
    for (int l = 0; l < 2; ++l) {
      int idx = tid + l * 256;
      int r = idx >> 2;
      int kv = (idx & 3) << 2;
      float4 v = make_float4(0.f, 0.f, 0.f, 0.f);
      int grow = row0 + r;
      if (grow < M) v = *reinterpret_cast<const float4*>(A + (size_t)grow * Kdim + k0 + kv);
      if (RELU) {
        v.x = fmaxf(v.x, 0.f); v.y = fmaxf(v.y, 0.f);
        v.z = fmaxf(v.z, 0.f); v.w = fmaxf(v.w, 0.f);
      }
      As[kv + 0][r] = v.x; As[kv + 1][r] = v.y;
      As[kv + 2][r] = v.z; As[kv + 3][r] = v.w;
    }
    // stage B: BK x BN
    {
      int r = tid >> 4;
      int cv = (tid & 15) << 2;
      *reinterpret_cast<float4*>(&Bs[r][cv]) =
          *reinterpret_cast<const float4*>(B + (size_t)(k0 + r) * KD + col0 + cv);
    }
    __syncthreads();
#pragma unroll
    for (int k = 0; k < BK; ++k) {
      float a[TM], b[TN];
#pragma unroll
      for (int i = 0; i < TM; ++i) a[i] = As[k][ty * TM + i];
#pragma unroll
      for (int j = 0; j < TN; ++j) b[j] = Bs[k][tx * TN + j];
#pragma unroll
      for (int i = 0; i < TM; ++i)
#pragma unroll
        for (int j = 0; j < TN; ++j)
          acc[i][j] = fmaf(a[i], b[j], acc[i][j]);
    }
  }
}

__global__ __launch_bounds__(256) void k_gemm_plain(
    const float* __restrict__ A, const float* __restrict__ B,
    float* __restrict__ C, int M, int Kdim)
{
  __shared__ float As[BK][BM + 4];
  __shared__ float Bs[BK][BN];
  float acc[TM][TN] = {};
  int row0 = blockIdx.x * BM, col0 = blockIdx.y * BN;
  int tid = threadIdx.x;
  gemm_tile_acc<false>(acc, A, M, Kdim, B, row0, col0, tid, As, Bs);
  int ty = tid >> 4, tx = tid & 15;
#pragma unroll
  for (int i = 0; i < TM; ++i) {
    int r = row0 + ty * TM + i;
    if (r < M) {
      float4 o = make_float4(acc[i][0], acc[i][1], acc[i][2], acc[i][3]);
      *reinterpret_cast<float4*>(C + (size_t)r * KD + col0 + tx * TN) = o;
    }
  }
}

// out_a = sig(res_w)*[relu(r_wb)@W_rel_wb] + (1-sig)*[feat_a@W_res_a + b]
__global__ __launch_bounds__(256) void k_out_a(
    const float* __restrict__ r_wb, const float* __restrict__ W_rel,
    const float* __restrict__ feat, const float* __restrict__ W_res,
    const float* __restrict__ b_res, const float* __restrict__ res_w,
    float* __restrict__ outp, int M)
{
  __shared__ float As[BK][BM + 4];
  __shared__ float Bs[BK][BN];
  float acc1[TM][TN] = {};
  float acc2[TM][TN] = {};
  int row0 = blockIdx.x * BM, col0 = blockIdx.y * BN;
  int tid = threadIdx.x;
  gemm_tile_acc<true >(acc1, r_wb, M, KD,  W_rel, row0, col0, tid, As, Bs);
  gemm_tile_acc<false>(acc2, feat, M, DIN, W_res, row0, col0, tid, As, Bs);
  float g = 1.f / (1.f + expf(-res_w[0]));
  int ty = tid >> 4, tx = tid & 15;
  int col = col0 + tx * TN;
  float4 bv = *reinterpret_cast<const float4*>(b_res + col);
#pragma unroll
  for (int i = 0; i < TM; ++i) {
    int r = row0 + ty * TM + i;
    if (r < M) {
      float4 o;
      o.x = g * acc1[i][0] + (1.f - g) * (acc2[i][0] + bv.x);
      o.y = g * acc1[i][1] + (1.f - g) * (acc2[i][1] + bv.y);
      o.z = g * acc1[i][2] + (1.f - g) * (acc2[i][2] + bv.z);
      o.w = g * acc1[i][3] + (1.f - g) * (acc2[i][3] + bv.w);
      *reinterpret_cast<float4*>(outp + (size_t)r * KD + col) = o;
    }
  }
}

// out_p = sig*[ww*(relu(r_w)@W_rw) + wc*(relu(r_c)@W_rc)] + (1-sig)*[feat_p@W_res_p + b]
__global__ __launch_bounds__(256) void k_out_p(
    const float* __restrict__ r_w, const float* __restrict__ W_rw,
    const float* __restrict__ r_c, const float* __restrict__ W_rc,
    const float* __restrict__ feat, const float* __restrict__ W_res,
    const float* __restrict__ b_res, const float* __restrict__ res_w,
    const float* __restrict__ ww, const float* __restrict__ wc,
    float* __restrict__ outp, int M)
{
  __shared__ float As[BK][BM + 4];
  __shared__ float Bs[BK][BN];
  float accw[TM][TN] = {};
  float accc[TM][TN] = {};
  float accr[TM][TN] = {};
  int row0 = blockIdx.x * BM, col0 = blockIdx.y * BN;
  int tid = threadIdx.x;
  gemm_tile_acc<true >(accw, r_w, M, KD,  W_rw,  row0, col0, tid, As, Bs);
  gemm_tile_acc<true >(accc, r_c, M, KD,  W_rc,  row0, col0, tid, As, Bs);
  gemm_tile_acc<false>(accr, feat, M, DIN, W_res, row0, col0, tid, As, Bs);
  float g = 1.f / (1.f + expf(-res_w[0]));
  int ty = tid >> 4, tx = tid & 15;
  int col = col0 + tx * TN;
  int head = col >> 5;
  float4 bv = *reinterpret_cast<const float4*>(b_res + col);
#pragma unroll
  for (int i = 0; i < TM; ++i) {
    int r = row0 + ty * TM + i;
    if (r < M) {
      float wwv = ww[(size_t)r * KH + head];
      float wcv = wc[(size_t)r * KH + head];
      float4 o;
      o.x = g * (wwv * accw[i][0] + wcv * accc[i][0]) + (1.f - g) * (accr[i][0] + bv.x);
      o.y = g * (wwv * accw[i][1] + wcv * accc[i][1]) + (1.f - g) * (accr[i][1] + bv.y);
      o.z = g * (wwv * accw[i][2] + wcv * accc[i][2]) + (1.f - g) * (accr[i][2] + bv.z);
      o.w = g * (wwv * accw[i][3] + wcv * accc[i][3]) + (1.f - g) * (accr[i][3] + bv.w);
      *reinterpret_cast<float4*>(outp + (size_t)r * KD + col) = o;
    }
  }
}

// per-node attention dots: o_i[n*8+k] = dot(f[n,k*32:(k+1)*32], v_i[k*64 .. +32]) (v base pre-offset)
__global__ void k_node_dots(
    const float* __restrict__ f, int N,
    const float* __restrict__ a0, float* __restrict__ o0,
    const float* __restrict__ a1, float* __restrict__ o1,
    const float* __restrict__ a2, float* __restrict__ o2)
{
  int idx = blockIdx.x * blockDim.x + threadIdx.x;
  if (idx >= N * KH) return;
  int n = idx >> 3, k = idx & 7;
  const float* fr = f + (size_t)n * KD + k * DH;
  float d0 = 0.f, d1 = 0.f, d2 = 0.f;
#pragma unroll
  for (int i = 0; i < DH; i += 4) {
    float4 fv = *reinterpret_cast<const float4*>(fr + i);
    if (a0) {
      float4 v = *reinterpret_cast<const float4*>(a0 + k * 64 + i);
      d0 += fv.x * v.x + fv.y * v.y + fv.z * v.z + fv.w * v.w;
    }
    if (a1) {
      float4 v = *reinterpret_cast<const float4*>(a1 + k * 64 + i);
      d1 += fv.x * v.x + fv.y * v.y + fv.z * v.z + fv.w * v.w;
    }
    if (a2) {
      float4 v = *reinterpret_cast<const float4*>(a2 + k * 64 + i);
      d2 += fv.x * v.x + fv.y * v.y + fv.z * v.z + fv.w * v.w;
    }
  }
  if (o0) o0[idx] = d0;
  if (o1) o1[idx] = d1;
  if (o2) o2[idx] = d2;
}

// per-edge: a = exp(leaky(el[src]+er[dst])), accumulate s[dst]
__global__ void k_edge1(
    const int* __restrict__ src, const int* __restrict__ dst, int E,
    const float* __restrict__ el, const float* __restrict__ er,
    float* __restrict__ a_out, float* __restrict__ s)
{
  int e = blockIdx.x * blockDim.x + threadIdx.x;
  if (e >= E) return;
  int si = src[e], di = dst[e];
  float4 l0 = *reinterpret_cast<const float4*>(el + (size_t)si * KH);
  float4 l1 = *reinterpret_cast<const float4*>(el + (size_t)si * KH + 4);
  float4 r0 = *reinterpret_cast<const float4*>(er + (size_t)di * KH);
  float4 r1 = *reinterpret_cast<const float4*>(er + (size_t)di * KH + 4);
  float av[KH];
  av[0] = expf(leakyf(l0.x + r0.x)); av[1] = expf(leakyf(l0.y + r0.y));
  av[2] = expf(leakyf(l0.z + r0.z)); av[3] = expf(leakyf(l0.w + r0.w));
  av[4] = expf(leakyf(l1.x + r1.x)); av[5] = expf(leakyf(l1.y + r1.y));
  av[6] = expf(leakyf(l1.z + r1.z)); av[7] = expf(leakyf(l1.w + r1.w));
  float4 o0 = make_float4(av[0], av[1], av[2], av[3]);
  float4 o1 = make_float4(av[4], av[5], av[6], av[7]);
  *reinterpret_cast<float4*>(a_out + (size_t)e * KH) = o0;
  *reinterpret_cast<float4*>(a_out + (size_t)e * KH + 4) = o1;
  float* sp = s + (size_t)di * KH;
#pragma unroll
  for (int k = 0; k < KH; ++k) unsafeAtomicAdd(sp + k, av[k]);
}

// scatter messages: out[dst] += fs[src] * a/s[dst]   (256 threads = one edge slice)
__global__ void k_edge_agg(
    const int* __restrict__ src, const int* __restrict__ dst, int E,
    const float* __restrict__ a, const float* __restrict__ s,
    const float* __restrict__ fs, float* __restrict__ outp)
{
  int t = threadIdx.x;
  int k = t >> 5;
  for (int e = blockIdx.x; e < E; e += gridDim.x) {
    int si = src[e], di = dst[e];
    float an = a[(size_t)e * KH + k] / s[(size_t)di * KH + k];
    float v = fs[(size_t)si * KD + t] * an;
    unsafeAtomicAdd(outp + (size_t)di * KD + t, v);
  }
}

// tiny pre-contractions: W_eff = sum_d W[:, k*32+d] * attn[k, off+d]
__global__ void k_weff(
    const float* __restrict__ Wmnp, const float* __restrict__ Wrw,
    const float* __restrict__ Wrc, const float* __restrict__ attn,
    float* __restrict__ enp, float* __restrict__ ew, float* __restrict__ ec)
{
  int idx = blockIdx.x * blockDim.x + threadIdx.x;
  if (idx < DIN * KH) {
    int c = idx >> 3, k = idx & 7;
    float sum = 0.f;
    for (int d = 0; d < DH; ++d) sum += Wmnp[(size_t)c * KD + k * DH + d] * attn[k * 64 + d];
    enp[idx] = sum;
  } else if (idx < DIN * KH + KD * KH) {
    int j = idx - DIN * KH;
    int c = j >> 3, k = j & 7;
    float sum = 0.f;
    for (int d = 0; d < DH; ++d) sum += Wrw[(size_t)c * KD + k * DH + d] * attn[k * 64 + 32 + d];
    ew[j] = sum;
  } else if (idx < DIN * KH + 2 * KD * KH) {
    int j = idx - DIN * KH - KD * KH;
    int c = j >> 3, k = j & 7;
    float sum = 0.f;
    for (int d = 0; d < DH; ++d) sum += Wrc[(size_t)c * KD + k * DH + d] * attn[k * 64 + 32 + d];
    ec[j] = sum;
  }
}

// skinny GEMM: out[M,8] = op(A[M,Kdim]) @ W[Kdim,8]
template<bool RELU>
__global__ __launch_bounds__(256) void k_skinny(
    const float* __restrict__ A, int M, int Kdim,
    const float* __restrict__ W, float* __restrict__ outp)
{
  __shared__ float Ws[KD * KH];
  int tid = threadIdx.x;
  for (int i = tid; i < Kdim * KH; i += 256) Ws[i] = W[i];
  __syncthreads();
  int r = blockIdx.x * 32 + (tid >> 3);
  int k = tid & 7;
  if (r >= M) return;
  const float* Ar = A + (size_t)r * Kdim;
  float acc = 0.f;
  for (int c = 0; c < Kdim; c += 4) {
    float4 av = *reinterpret_cast<const float4*>(Ar + c);
    if (RELU) {
      av.x = fmaxf(av.x, 0.f); av.y = fmaxf(av.y, 0.f);
      av.z = fmaxf(av.z, 0.f); av.w = fmaxf(av.w, 0.f);
    }
    acc += av.x * Ws[(c + 0) * KH + k] + av.y * Ws[(c + 1) * KH + k]
         + av.z * Ws[(c + 2) * KH + k] + av.w * Ws[(c + 3) * KH + k];
  }
  outp[(size_t)r * KH + k] = acc;
}

// macro softmax weights over 2 relations
__global__ void k_weights(
    const float* __restrict__ npdot, const float* __restrict__ scw,
    const float* __restrict__ scc, float* __restrict__ ww,
    float* __restrict__ wc, int N8)
{
  int idx = blockIdx.x * blockDim.x + threadIdx.x;
  if (idx >= N8) return;
  float nd = npdot[idx];
  float lw = leakyf(nd + scw[idx]);
  float lc = leakyf(nd + scc[idx]);
  float m = fmaxf(lw, lc);
  float e1 = expf(lw - m), e2 = expf(lc - m);
  float inv = 1.f / (e1 + e2);
  ww[idx] = e1 * inv;
  wc[idx] = e2 * inv;
}

extern "C" void kernel_launch(void* const* d_in, const int* in_sizes, int n_in,
                              void* d_out, int out_size, void* d_ws, size_t ws_size,
                              hipStream_t stream)
{
  const float* feat_a  = (const float*)d_in[0];
  const float* feat_p  = (const float*)d_in[1];
  const float* W_mic_a = (const float*)d_in[2];
  const float* W_mic_p = (const float*)d_in[3];
  const float* attn_a  = (const float*)d_in[4];
  const float* attn_p  = (const float*)d_in[5];
  const float* W_mnp   = (const float*)d_in[7];
  const float* W_rw    = (const float*)d_in[8];
  const float* W_rwb   = (const float*)d_in[9];
  const float* W_rc    = (const float*)d_in[10];
  const float* attn_m  = (const float*)d_in[11];
  const float* W_res_a = (const float*)d_in[12];
  const float* b_res_a = (const float*)d_in[13];
  const float* W_res_p = (const float*)d_in[14];
  const float* b_res_p = (const float*)d_in[15];
  const float* rw_a    = (const float*)d_in[16];
  const float* rw_p    = (const float*)d_in[17];
  const int* w_src  = (const int*)d_in[18];
  const int* w_dst  = (const int*)d_in[19];
  const int* wbsrc  = (const int*)d_in[20];
  const int* wbdst  = (const int*)d_in[21];
  const int* c_src  = (const int*)d_in[22];
  const int* c_dst  = (const int*)d_in[23];
  const int Ew = in_sizes[18], Ewb = in_sizes[20], Ec = in_sizes[22];

  float* ws = (float*)d_ws;
  const size_t SA = (size_t)NAU * KD;      // 12.8M
  const size_t SP = (size_t)NPA * KD;      // 25.6M
  float* fa    = ws;                       // SA
  float* fp    = ws + SA;                  // SP
  float* r_w   = ws + SA + SP;             // SP
  float* r_wb  = r_w + SP;                 // SA
  float* r_c   = r_wb + SA;                // SP
  float* a_buf = r_c + SP;                 // 8M (max E*8)
  float* elA   = a_buf + 8000000;          // NA*8
  float* erA   = elA + (size_t)NAU * KH;
  float* elP   = erA + (size_t)NAU * KH;   // NP*8
  float* erPa  = elP + (size_t)NPA * KH;
  float* erPp  = erPa + (size_t)NPA * KH;
  float* s_w   = erPp + (size_t)NPA * KH;  // NP*8
  float* s_wb  = s_w + (size_t)NPA * KH;   // NA*8
  float* s_c   = s_wb + (size_t)NAU * KH;  // NP*8
  float* npdot = s_c + (size_t)NPA * KH;
  float* scw   = npdot + (size_t)NPA * KH;
  float* scc   = scw + (size_t)NPA * KH;
  float* wwb   = scc + (size_t)NPA * KH;
  float* wcb   = wwb + (size_t)NPA * KH;
  float* effnp = wcb + (size_t)NPA * KH;   // 128*8
  float* effw  = effnp + DIN * KH;         // 256*8
  float* effc  = effw + KD * KH;           // 256*8

  float* out_a = (float*)d_out;
  float* out_p = (float*)d_out + SA;

  // zero r_w|r_wb|r_c (contiguous) and s_w|s_wb|s_c (contiguous)
  hipMemsetAsync(r_w, 0, (SP + SA + SP) * sizeof(float), stream);
  hipMemsetAsync(s_w, 0, ((size_t)(NPA + NAU + NPA) * KH) * sizeof(float), stream);

  // micro projections
  {
    dim3 g((NAU + BM - 1) / BM, KD / BN);
    k_gemm_plain<<<g, 256, 0, stream>>>(feat_a, W_mic_a, fa, NAU, DIN);
  }
  {
    dim3 g((NPA + BM - 1) / BM, KD / BN);
    k_gemm_plain<<<g, 256, 0, stream>>>(feat_p, W_mic_p, fp, NPA, DIN);
  }

  // node attention dots
  k_node_dots<<<(NAU * KH + 255) / 256, 256, 0, stream>>>(
      fa, NAU, attn_a, elA, attn_p + 32, erA, nullptr, nullptr);
  k_node_dots<<<(NPA * KH + 255) / 256, 256, 0, stream>>>(
      fp, NPA, attn_p, elP, attn_a + 32, erPa, attn_p + 32, erPp);

  // relation: writes (author->paper)  el=elA[src], er=erPa[dst]
  k_edge1<<<(Ew + 255) / 256, 256, 0, stream>>>(w_src, w_dst, Ew, elA, erPa, a_buf, s_w);
  k_edge_agg<<<4096, 256, 0, stream>>>(w_src, w_dst, Ew, a_buf, s_w, fa, r_w);

  // relation: written_by (paper->author)  el=elP[src], er=erA[dst]
  k_edge1<<<(Ewb + 255) / 256, 256, 0, stream>>>(wbsrc, wbdst, Ewb, elP, erA, a_buf, s_wb);
  k_edge_agg<<<4096, 256, 0, stream>>>(wbsrc, wbdst, Ewb, a_buf, s_wb, fp, r_wb);

  // relation: cites (paper->paper)  el=elP[src], er=erPp[dst]
  k_edge1<<<(Ec + 255) / 256, 256, 0, stream>>>(c_src, c_dst, Ec, elP, erPp, a_buf, s_c);
  k_edge_agg<<<8192, 256, 0, stream>>>(c_src, c_dst, Ec, a_buf, s_c, fp, r_c);

  // out_a: fused rel+residual GEMM
  {
    dim3 g((NAU + BM - 1) / BM, KD / BN);
    k_out_a<<<g, 256, 0, stream>>>(r_wb, W_rwb, feat_a, W_res_a, b_res_a, rw_a, out_a, NAU);
  }

  // macro attention: pre-contract, skinny score GEMMs, softmax weights
  k_weff<<<20, 256, 0, stream>>>(W_mnp, W_rw, W_rc, attn_m, effnp, effw, effc);
  k_skinny<false><<<(NPA + 31) / 32, 256, 0, stream>>>(feat_p, NPA, DIN, effnp, npdot);
  k_skinny<true ><<<(NPA + 31) / 32, 256, 0, stream>>>(r_w, NPA, KD, effw, scw);
  k_skinny<true ><<<(NPA + 31) / 32, 256, 0, stream>>>(r_c, NPA, KD, effc, scc);
  k_weights<<<(NPA * KH + 255) / 256, 256, 0, stream>>>(npdot, scw, scc, wwb, wcb, NPA * KH);

  // out_p: fused triple GEMM with macro weights + residual
  {
    dim3 g((NPA + BM - 1) / BM, KD / BN);
    k_out_p<<<g, 256, 0, stream>>>(r_w, W_rw, r_c, W_rc, feat_p, W_res_p, b_res_p, rw_p,
                                   wwb, wcb, out_p, NPA);
  }
}

// Round 2
// 2008.807 us; speedup vs baseline: 1.9260x; 1.9260x over previous
//
#include <hip/hip_runtime.h>
#include <cstddef>
#include <cstdint>

#define NAU 50000
#define NPA 100000
#define KH 8
#define DH 32
#define KD 256
#define DIN 128
#define SLOPE 0.2f

// ---------------- tiled f32 GEMM (N fixed = 256 cols) ----------------
#define BM 128
#define BN 64
#define BK 16
#define TM 8
#define TN 4
// 256 threads per block, ty=tid/16 (row group), tx=tid%16 (col group)

__device__ __forceinline__ float leakyf(float x) { return x >= 0.f ? x : SLOPE * x; }

template<bool RELU>
__device__ __forceinline__ void gemm_tile_acc(
    float acc[TM][TN],
    const float* __restrict__ A, int M, int Kdim,
    const float* __restrict__ B,   // Kdim x 256 row-major
    int row0, int col0, int tid,
    float (*As)[BM + 4], float (*Bs)[BN])
{
  const int ty = tid >> 4, tx = tid & 15;
  for (int k0 = 0; k0 < Kdim; k0 += BK) {
    __syncthreads();
    // stage A: BM x BK
#pragma unroll
    for (int l = 0; l < 2; ++l) {
      int idx = tid + l * 256;
      int r = idx >> 2;
      int kv = (idx & 3) << 2;
      float4 v = make_float4(0.f, 0.f, 0.f, 0.f);
      int grow = row0 + r;
      if (grow < M) v = *reinterpret_cast<const float4*>(A + (size_t)grow * Kdim + k0 + kv);
      if (RELU) {
        v.x = fmaxf(v.x, 0.f); v.y = fmaxf(v.y, 0.f);
        v.z = fmaxf(v.z, 0.f); v.w = fmaxf(v.w, 0.f);
      }
      As[kv + 0][r] = v.x; As[kv + 1][r] = v.y;
      As[kv + 2][r] = v.z; As[kv + 3][r] = v.w;
    }
    // stage B: BK x BN
    {
      int r = tid >> 4;
      int cv = (tid & 15) << 2;
      *reinterpret_cast<float4*>(&Bs[r][cv]) =
          *reinterpret_cast<const float4*>(B + (size_t)(k0 + r) * KD + col0 + cv);
    }
    __syncthreads();
#pragma unroll
    for (int k = 0; k < BK; ++k) {
      float a[TM], b[TN];
#pragma unroll
      for (int i = 0; i < TM; ++i) a[i] = As[k][ty * TM + i];
#pragma unroll
      for (int j = 0; j < TN; ++j) b[j] = Bs[k][tx * TN + j];
#pragma unroll
      for (int i = 0; i < TM; ++i)
#pragma unroll
        for (int j = 0; j < TN; ++j)
          acc[i][j] = fmaf(a[i], b[j], acc[i][j]);
    }
  }
}

__global__ __launch_bounds__(256) void k_gemm_plain(
    const float* __restrict__ A, const float* __restrict__ B,
    float* __restrict__ C, int M, int Kdim)
{
  __shared__ float As[BK][BM + 4];
  __shared__ float Bs[BK][BN];
  float acc[TM][TN] = {};
  int row0 = blockIdx.x * BM, col0 = blockIdx.y * BN;
  int tid = threadIdx.x;
  gemm_tile_acc<false>(acc, A, M, Kdim, B, row0, col0, tid, As, Bs);
  int ty = tid >> 4, tx = tid & 15;
#pragma unroll
  for (int i = 0; i < TM; ++i) {
    int r = row0 + ty * TM + i;
    if (r < M) {
      float4 o = make_float4(acc[i][0], acc[i][1], acc[i][2], acc[i][3]);
      *reinterpret_cast<float4*>(C + (size_t)r * KD + col0 + tx * TN) = o;
    }
  }
}

// out_a = sig(res_w)*[relu(r_wb)@W_rel_wb] + (1-sig)*[feat_a@W_res_a + b]
__global__ __launch_bounds__(256) void k_out_a(
    const float* __restrict__ r_wb, const float* __restrict__ W_rel,
    const float* __restrict__ feat, const float* __restrict__ W_res,
    const float* __restrict__ b_res, const float* __restrict__ res_w,
    float* __restrict__ outp, int M)
{
  __shared__ float As[BK][BM + 4];
  __shared__ float Bs[BK][BN];
  float acc1[TM][TN] = {};
  float acc2[TM][TN] = {};
  int row0 = blockIdx.x * BM, col0 = blockIdx.y * BN;
  int tid = threadIdx.x;
  gemm_tile_acc<true >(acc1, r_wb, M, KD,  W_rel, row0, col0, tid, As, Bs);
  gemm_tile_acc<false>(acc2, feat, M, DIN, W_res, row0, col0, tid, As, Bs);
  float g = 1.f / (1.f + expf(-res_w[0]));
  int ty = tid >> 4, tx = tid & 15;
  int col = col0 + tx * TN;
  float4 bv = *reinterpret_cast<const float4*>(b_res + col);
#pragma unroll
  for (int i = 0; i < TM; ++i) {
    int r = row0 + ty * TM + i;
    if (r < M) {
      float4 o;
      o.x = g * acc1[i][0] + (1.f - g) * (acc2[i][0] + bv.x);
      o.y = g * acc1[i][1] + (1.f - g) * (acc2[i][1] + bv.y);
      o.z = g * acc1[i][2] + (1.f - g) * (acc2[i][2] + bv.z);
      o.w = g * acc1[i][3] + (1.f - g) * (acc2[i][3] + bv.w);
      *reinterpret_cast<float4*>(outp + (size_t)r * KD + col) = o;
    }
  }
}

// out_p = sig*[ww*(relu(r_w)@W_rw) + wc*(relu(r_c)@W_rc)] + (1-sig)*[feat_p@W_res_p + b]
__global__ __launch_bounds__(256) void k_out_p(
    const float* __restrict__ r_w, const float* __restrict__ W_rw,
    const float* __restrict__ r_c, const float* __restrict__ W_rc,
    const float* __restrict__ feat, const float* __restrict__ W_res,
    const float* __restrict__ b_res, const float* __restrict__ res_w,
    const float* __restrict__ ww, const float* __restrict__ wc,
    float* __restrict__ outp, int M)
{
  __shared__ float As[BK][BM + 4];
  __shared__ float Bs[BK][BN];
  float accw[TM][TN] = {};
  float accc[TM][TN] = {};
  float accr[TM][TN] = {};
  int row0 = blockIdx.x * BM, col0 = blockIdx.y * BN;
  int tid = threadIdx.x;
  gemm_tile_acc<true >(accw, r_w, M, KD,  W_rw,  row0, col0, tid, As, Bs);
  gemm_tile_acc<true >(accc, r_c, M, KD,  W_rc,  row0, col0, tid, As, Bs);
  gemm_tile_acc<false>(accr, feat, M, DIN, W_res, row0, col0, tid, As, Bs);
  float g = 1.f / (1.f + expf(-res_w[0]));
  int ty = tid >> 4, tx = tid & 15;
  int col = col0 + tx * TN;
  int head = col >> 5;
  float4 bv = *reinterpret_cast<const float4*>(b_res + col);
#pragma unroll
  for (int i = 0; i < TM; ++i) {
    int r = row0 + ty * TM + i;
    if (r < M) {
      float wwv = ww[(size_t)r * KH + head];
      float wcv = wc[(size_t)r * KH + head];
      float4 o;
      o.x = g * (wwv * accw[i][0] + wcv * accc[i][0]) + (1.f - g) * (accr[i][0] + bv.x);
      o.y = g * (wwv * accw[i][1] + wcv * accc[i][1]) + (1.f - g) * (accr[i][1] + bv.y);
      o.z = g * (wwv * accw[i][2] + wcv * accc[i][2]) + (1.f - g) * (accr[i][2] + bv.z);
      o.w = g * (wwv * accw[i][3] + wcv * accc[i][3]) + (1.f - g) * (accr[i][3] + bv.w);
      *reinterpret_cast<float4*>(outp + (size_t)r * KD + col) = o;
    }
  }
}

// per-node attention dots
__global__ void k_node_dots(
    const float* __restrict__ f, int N,
    const float* __restrict__ a0, float* __restrict__ o0,
    const float* __restrict__ a1, float* __restrict__ o1,
    const float* __restrict__ a2, float* __restrict__ o2)
{
  int idx = blockIdx.x * blockDim.x + threadIdx.x;
  if (idx >= N * KH) return;
  int n = idx >> 3, k = idx & 7;
  const float* fr = f + (size_t)n * KD + k * DH;
  float d0 = 0.f, d1 = 0.f, d2 = 0.f;
#pragma unroll
  for (int i = 0; i < DH; i += 4) {
    float4 fv = *reinterpret_cast<const float4*>(fr + i);
    if (a0) {
      float4 v = *reinterpret_cast<const float4*>(a0 + k * 64 + i);
      d0 += fv.x * v.x + fv.y * v.y + fv.z * v.z + fv.w * v.w;
    }
    if (a1) {
      float4 v = *reinterpret_cast<const float4*>(a1 + k * 64 + i);
      d1 += fv.x * v.x + fv.y * v.y + fv.z * v.z + fv.w * v.w;
    }
    if (a2) {
      float4 v = *reinterpret_cast<const float4*>(a2 + k * 64 + i);
      d2 += fv.x * v.x + fv.y * v.y + fv.z * v.z + fv.w * v.w;
    }
  }
  if (o0) o0[idx] = d0;
  if (o1) o1[idx] = d1;
  if (o2) o2[idx] = d2;
}

// ---------------- CSR build ----------------
__global__ void k_hist(const int* __restrict__ dst, int E, int* __restrict__ cnt) {
  int e = blockIdx.x * 256 + threadIdx.x;
  if (e < E) atomicAdd(&cnt[dst[e]], 1);
}

__global__ void k_scan1(const int* __restrict__ cnt, int n,
                        int* __restrict__ off, int* __restrict__ bsum) {
  __shared__ int sm[256];
  int t = threadIdx.x;
  int i = blockIdx.x * 256 + t;
  int v = (i < n) ? cnt[i] : 0;
  sm[t] = v; __syncthreads();
  for (int o = 1; o < 256; o <<= 1) {
    int x = (t >= o) ? sm[t - o] : 0;
    __syncthreads();
    sm[t] += x;
    __syncthreads();
  }
  if (i < n) off[i] = sm[t] - v;            // exclusive within block
  if (t == 255) bsum[blockIdx.x] = sm[255]; // block total
}

__global__ void k_scan2(int* __restrict__ bsum, int nb) {
  __shared__ int sm[512];
  int t = threadIdx.x;
  int v = (t < nb) ? bsum[t] : 0;
  sm[t] = v; __syncthreads();
  for (int o = 1; o < 512; o <<= 1) {
    int x = (t >= o) ? sm[t - o] : 0;
    __syncthreads();
    sm[t] += x;
    __syncthreads();
  }
  if (t < nb) bsum[t] = sm[t] - v;          // exclusive block offsets
}

__global__ void k_scan3(int* __restrict__ off, int n, const int* __restrict__ bsum) {
  int i = blockIdx.x * 256 + threadIdx.x;
  if (i < n) off[i] += bsum[blockIdx.x];
}

__global__ void k_scatter(const int* __restrict__ dst, int E,
                          const int* __restrict__ off, int* __restrict__ cur,
                          int* __restrict__ eidx) {
  int e = blockIdx.x * 256 + threadIdx.x;
  if (e >= E) return;
  int d = dst[e];
  int p = atomicAdd(&cur[d], 1);
  eidx[off[d] + p] = e;
}

// ---------------- dst-centric fused attention + aggregation ----------------
// block = one dst node, 256 threads = its (k,d) slots. Single pass:
// s_k = sum_e exp(leaky(el[src,k]+er[d,k]));  acc_t = sum_e fs[src,t]*a_e
// out = relu(acc/s)   (normalization factors out of the sum)
__global__ __launch_bounds__(256) void k_agg_dst(
    const int* __restrict__ eidx, const int* __restrict__ off_,
    const int* __restrict__ cnt_, const int* __restrict__ src,
    const float* __restrict__ el, const float* __restrict__ er,
    const float* __restrict__ fs, float* __restrict__ outp)
{
  __shared__ int ssi[256];
  int d = blockIdx.x;
  int t = threadIdx.x;
  int k = t >> 5;
  int c = cnt_[d];
  float acc = 0.f;
  float s = 0.f;
  if (c > 0) {
    int base = off_[d];
    float erk = er[(size_t)d * KH + k];
    for (int j0 = 0; j0 < c; j0 += 256) {
      int m = min(256, c - j0);
      __syncthreads();
      if (t < m) ssi[t] = src[eidx[base + j0 + t]];
      __syncthreads();
      for (int j = 0; j < m; ++j) {
        int si = ssi[j];
        float a = __expf(leakyf(el[(size_t)si * KH + k] + erk));
        s += a;
        acc = fmaf(fs[(size_t)si * KD + t], a, acc);
      }
    }
    acc = fmaxf(acc / s, 0.f);
  }
  outp[(size_t)d * KD + t] = acc;
}

// tiny pre-contractions
__global__ void k_weff(
    const float* __restrict__ Wmnp, const float* __restrict__ Wrw,
    const float* __restrict__ Wrc, const float* __restrict__ attn,
    float* __restrict__ enp, float* __restrict__ ew, float* __restrict__ ec)
{
  int idx = blockIdx.x * blockDim.x + threadIdx.x;
  if (idx < DIN * KH) {
    int c = idx >> 3, k = idx & 7;
    float sum = 0.f;
    for (int d = 0; d < DH; ++d) sum += Wmnp[(size_t)c * KD + k * DH + d] * attn[k * 64 + d];
    enp[idx] = sum;
  } else if (idx < DIN * KH + KD * KH) {
    int j = idx - DIN * KH;
    int c = j >> 3, k = j & 7;
    float sum = 0.f;
    for (int d = 0; d < DH; ++d) sum += Wrw[(size_t)c * KD + k * DH + d] * attn[k * 64 + 32 + d];
    ew[j] = sum;
  } else if (idx < DIN * KH + 2 * KD * KH) {
    int j = idx - DIN * KH - KD * KH;
    int c = j >> 3, k = j & 7;
    float sum = 0.f;
    for (int d = 0; d < DH; ++d) sum += Wrc[(size_t)c * KD + k * DH + d] * attn[k * 64 + 32 + d];
    ec[j] = sum;
  }
}

// skinny GEMM: out[M,8] = op(A[M,Kdim]) @ W[Kdim,8]
template<bool RELU>
__global__ __launch_bounds__(256) void k_skinny(
    const float* __restrict__ A, int M, int Kdim,
    const float* __restrict__ W, float* __restrict__ outp)
{
  __shared__ float Ws[KD * KH];
  int tid = threadIdx.x;
  for (int i = tid; i < Kdim * KH; i += 256) Ws[i] = W[i];
  __syncthreads();
  int r = blockIdx.x * 32 + (tid >> 3);
  int k = tid & 7;
  if (r >= M) return;
  const float* Ar = A + (size_t)r * Kdim;
  float acc = 0.f;
  for (int c = 0; c < Kdim; c += 4) {
    float4 av = *reinterpret_cast<const float4*>(Ar + c);
    if (RELU) {
      av.x = fmaxf(av.x, 0.f); av.y = fmaxf(av.y, 0.f);
      av.z = fmaxf(av.z, 0.f); av.w = fmaxf(av.w, 0.f);
    }
    acc += av.x * Ws[(c + 0) * KH + k] + av.y * Ws[(c + 1) * KH + k]
         + av.z * Ws[(c + 2) * KH + k] + av.w * Ws[(c + 3) * KH + k];
  }
  outp[(size_t)r * KH + k] = acc;
}

// macro softmax weights over 2 relations
__global__ void k_weights(
    const float* __restrict__ npdot, const float* __restrict__ scw,
    const float* __restrict__ scc, float* __restrict__ ww,
    float* __restrict__ wc, int N8)
{
  int idx = blockIdx.x * blockDim.x + threadIdx.x;
  if (idx >= N8) return;
  float nd = npdot[idx];
  float lw = leakyf(nd + scw[idx]);
  float lc = leakyf(nd + scc[idx]);
  float m = fmaxf(lw, lc);
  float e1 = __expf(lw - m), e2 = __expf(lc - m);
  float inv = 1.f / (e1 + e2);
  ww[idx] = e1 * inv;
  wc[idx] = e2 * inv;
}

static inline void run_relation(hipStream_t stream,
                                const int* src, const int* dst, int E, int n_dst,
                                int* cnt, int* cur, int* off, int* bsum, int* eidx,
                                const float* el, const float* er,
                                const float* fs, float* outp) {
  hipMemsetAsync(cnt, 0, (size_t)n_dst * sizeof(int), stream);
  hipMemsetAsync(cur, 0, (size_t)n_dst * sizeof(int), stream);
  int nb = (n_dst + 255) / 256;
  k_hist<<<(E + 255) / 256, 256, 0, stream>>>(dst, E, cnt);
  k_scan1<<<nb, 256, 0, stream>>>(cnt, n_dst, off, bsum);
  k_scan2<<<1, 512, 0, stream>>>(bsum, nb);
  k_scan3<<<nb, 256, 0, stream>>>(off, n_dst, bsum);
  k_scatter<<<(E + 255) / 256, 256, 0, stream>>>(dst, E, off, cur, eidx);
  k_agg_dst<<<n_dst, 256, 0, stream>>>(eidx, off, cnt, src, el, er, fs, outp);
}

extern "C" void kernel_launch(void* const* d_in, const int* in_sizes, int n_in,
                              void* d_out, int out_size, void* d_ws, size_t ws_size,
                              hipStream_t stream)
{
  const float* feat_a  = (const float*)d_in[0];
  const float* feat_p  = (const float*)d_in[1];
  const float* W_mic_a = (const float*)d_in[2];
  const float* W_mic_p = (const float*)d_in[3];
  const float* attn_a  = (const float*)d_in[4];
  const float* attn_p  = (const float*)d_in[5];
  const float* W_mnp   = (const float*)d_in[7];
  const float* W_rw    = (const float*)d_in[8];
  const float* W_rwb   = (const float*)d_in[9];
  const float* W_rc    = (const float*)d_in[10];
  const float* attn_m  = (const float*)d_in[11];
  const float* W_res_a = (const float*)d_in[12];
  const float* b_res_a = (const float*)d_in[13];
  const float* W_res_p = (const float*)d_in[14];
  const float* b_res_p = (const float*)d_in[15];
  const float* rw_a    = (const float*)d_in[16];
  const float* rw_p    = (const float*)d_in[17];
  const int* w_src  = (const int*)d_in[18];
  const int* w_dst  = (const int*)d_in[19];
  const int* wbsrc  = (const int*)d_in[20];
  const int* wbdst  = (const int*)d_in[21];
  const int* c_src  = (const int*)d_in[22];
  const int* c_dst  = (const int*)d_in[23];
  const int Ew = in_sizes[18], Ewb = in_sizes[20], Ec = in_sizes[22];

  float* ws = (float*)d_ws;
  const size_t SA = (size_t)NAU * KD;      // 12.8M
  const size_t SP = (size_t)NPA * KD;      // 25.6M
  float* fa    = ws;                       // SA
  float* fp    = fa + SA;                  // SP
  float* r_w   = fp + SP;                  // SP
  float* r_wb  = r_w + SP;                 // SA
  float* r_c   = r_wb + SA;                // SP
  float* elA   = r_c + SP;                 // NA*8
  float* erA   = elA + (size_t)NAU * KH;
  float* elP   = erA + (size_t)NAU * KH;   // NP*8
  float* erPa  = elP + (size_t)NPA * KH;
  float* erPp  = erPa + (size_t)NPA * KH;
  float* npdot = erPp + (size_t)NPA * KH;
  float* scw   = npdot + (size_t)NPA * KH;
  float* scc   = scw + (size_t)NPA * KH;
  float* wwb   = scc + (size_t)NPA * KH;
  float* wcb   = wwb + (size_t)NPA * KH;
  float* effnp = wcb + (size_t)NPA * KH;   // 128*8
  float* effw  = effnp + DIN * KH;         // 256*8
  float* effc  = effw + KD * KH;           // 256*8
  int*   cnt   = (int*)(effc + KD * KH);   // 100000
  int*   cur   = cnt + NPA;
  int*   off   = cur + NPA;
  int*   bsum  = off + NPA;                // 512
  int*   eidx  = bsum + 512;               // up to 1M

  float* out_a = (float*)d_out;
  float* out_p = (float*)d_out + SA;

  // micro projections
  {
    dim3 g((NAU + BM - 1) / BM, KD / BN);
    k_gemm_plain<<<g, 256, 0, stream>>>(feat_a, W_mic_a, fa, NAU, DIN);
  }
  {
    dim3 g((NPA + BM - 1) / BM, KD / BN);
    k_gemm_plain<<<g, 256, 0, stream>>>(feat_p, W_mic_p, fp, NPA, DIN);
  }

  // node attention dots
  k_node_dots<<<(NAU * KH + 255) / 256, 256, 0, stream>>>(
      fa, NAU, attn_a, elA, attn_p + 32, erA, nullptr, nullptr);
  k_node_dots<<<(NPA * KH + 255) / 256, 256, 0, stream>>>(
      fp, NPA, attn_p, elP, attn_a + 32, erPa, attn_p + 32, erPp);

  // relations: CSR build + dst-centric fused aggregation (atomic-free)
  run_relation(stream, w_src, w_dst, Ew, NPA, cnt, cur, off, bsum, eidx,
               elA, erPa, fa, r_w);
  run_relation(stream, wbsrc, wbdst, Ewb, NAU, cnt, cur, off, bsum, eidx,
               elP, erA, fp, r_wb);
  run_relation(stream, c_src, c_dst, Ec, NPA, cnt, cur, off, bsum, eidx,
               elP, erPp, fp, r_c);

  // out_a: fused rel+residual GEMM
  {
    dim3 g((NAU + BM - 1) / BM, KD / BN);
    k_out_a<<<g, 256, 0, stream>>>(r_wb, W_rwb, feat_a, W_res_a, b_res_a, rw_a, out_a, NAU);
  }

  // macro attention: pre-contract, skinny score GEMMs, softmax weights
  k_weff<<<20, 256, 0, stream>>>(W_mnp, W_rw, W_rc, attn_m, effnp, effw, effc);
  k_skinny<false><<<(NPA + 31) / 32, 256, 0, stream>>>(feat_p, NPA, DIN, effnp, npdot);
  k_skinny<true ><<<(NPA + 31) / 32, 256, 0, stream>>>(r_w, NPA, KD, effw, scw);
  k_skinny<true ><<<(NPA + 31) / 32, 256, 0, stream>>>(r_c, NPA, KD, effc, scc);
  k_weights<<<(NPA * KH + 255) / 256, 256, 0, stream>>>(npdot, scw, scc, wwb, wcb, NPA * KH);

  // out_p: fused triple GEMM with macro weights + residual
  {
    dim3 g((NPA + BM - 1) / BM, KD / BN);
    k_out_p<<<g, 256, 0, stream>>>(r_w, W_rw, r_c, W_rc, feat_p, W_res_p, b_res_p, rw_p,
                                   wwb, wcb, out_p, NPA);
  }
}

// Round 3
// 1531.505 us; speedup vs baseline: 2.5263x; 1.3117x over previous
//
#include <hip/hip_runtime.h>
#include <hip/hip_bf16.h>
#include <cstddef>
#include <cstdint>

#define NAU 50000
#define NPA 100000
#define KH 8
#define DH 32
#define KD 256
#define DIN 128
#define SLOPE 0.2f

typedef __attribute__((ext_vector_type(8))) short short8;
typedef __attribute__((ext_vector_type(4))) float f32x4;

__device__ __forceinline__ float leakyf(float x) { return x >= 0.f ? x : SLOPE * x; }

__device__ __forceinline__ ushort f2b(float f) {
  __hip_bfloat16 h = __float2bfloat16(f);
  return *reinterpret_cast<ushort*>(&h);
}
__device__ __forceinline__ float b2f(ushort u) {
  __hip_bfloat16 h;
  *reinterpret_cast<ushort*>(&h) = u;
  return __bfloat162float(h);
}

// ---------------- MFMA split-bf16 GEMM ----------------
// C[M,256] = sum_p A_p[M,Kp] @ B_p[Kp,256]  (each product via hi/lo bf16 split)
// block: 256 thr = 4 waves; tile 64x64; wave quadrant 32x32 = 2x2 frags 16x16; k-step 32.

__device__ __forceinline__ short8 ldfrag(const ushort (*P)[40], int row, int kq) {
  const ushort* p0 = &P[row][kq * 4];
  ushort4 a = *reinterpret_cast<const ushort4*>(p0);
  ushort4 b = *reinterpret_cast<const ushort4*>(p0 + 16);
  short8 f;
  f[0] = (short)a.x; f[1] = (short)a.y; f[2] = (short)a.z; f[3] = (short)a.w;
  f[4] = (short)b.x; f[5] = (short)b.y; f[6] = (short)b.z; f[7] = (short)b.w;
  return f;
}

template<int NP, int EPI>
__global__ __launch_bounds__(256) void k_mfma(
    const float* __restrict__ A0, int K0, const ushort* __restrict__ B0h, const ushort* __restrict__ B0l,
    const float* __restrict__ A1, int K1, const ushort* __restrict__ B1h, const ushort* __restrict__ B1l,
    const float* __restrict__ A2, int K2, const ushort* __restrict__ B2h, const ushort* __restrict__ B2l,
    int M,
    const float* __restrict__ bres, const float* __restrict__ resw,
    const float* __restrict__ wwp, const float* __restrict__ wcp,
    float* __restrict__ outp)
{
  __shared__ ushort As[2][64][40];   // [hi/lo][row][k] pad 40 (2-way banks = free)
  __shared__ ushort Bs[2][64][40];   // [hi/lo][n][k]
  const int tid = threadIdx.x;
  const int row0 = blockIdx.x * 64, col0 = blockIdx.y * 64;
  const int wid = tid >> 6, lane = tid & 63;
  const int wr = wid >> 1, wc = wid & 1;
  const int kq = lane >> 4, rr = lane & 15;
  const int sr = tid >> 2;           // staging row 0..63
  const int sc = (tid & 3) << 3;     // staging k-chunk {0,8,16,24}

  f32x4 acc[NP][2][2] = {};

  const float*  Aps[3] = {A0, A1, A2};
  const ushort* Bhs[3] = {B0h, B1h, B2h};
  const ushort* Bls[3] = {B0l, B1l, B2l};
  const int     Kds[3] = {K0, K1, K2};

#pragma unroll
  for (int p = 0; p < NP; ++p) {
    const float*  A  = Aps[p];
    const ushort* Bh = Bhs[p];
    const ushort* Bl = Bls[p];
    const int     Kd = Kds[p];
    for (int k0 = 0; k0 < Kd; k0 += 32) {
      __syncthreads();
      // stage A (f32 -> hi/lo bf16 split in registers)
      {
        int gr = row0 + sr;
        float4 v0, v1;
        if (gr < M) {
          const float* ap = A + (size_t)gr * Kd + k0 + sc;
          v0 = *reinterpret_cast<const float4*>(ap);
          v1 = *reinterpret_cast<const float4*>(ap + 4);
        } else {
          v0 = make_float4(0.f, 0.f, 0.f, 0.f); v1 = v0;
        }
        float vb[8] = {v0.x, v0.y, v0.z, v0.w, v1.x, v1.y, v1.z, v1.w};
        union Pack { ushort u[8]; int4 v; } ph, pl;
#pragma unroll
        for (int i = 0; i < 8; ++i) {
          ushort h = f2b(vb[i]);
          ph.u[i] = h;
          pl.u[i] = f2b(vb[i] - b2f(h));
        }
        *reinterpret_cast<int4*>(&As[0][sr][sc]) = ph.v;
        *reinterpret_cast<int4*>(&As[1][sr][sc]) = pl.v;
      }
      // stage B^T (already split planes, [256][Kd])
      {
        const size_t bo = (size_t)(col0 + sr) * Kd + k0 + sc;
        *reinterpret_cast<int4*>(&Bs[0][sr][sc]) = *reinterpret_cast<const int4*>(Bh + bo);
        *reinterpret_cast<int4*>(&Bs[1][sr][sc]) = *reinterpret_cast<const int4*>(Bl + bo);
      }
      __syncthreads();

      short8 ah[2], al[2], bh[2], bl[2];
#pragma unroll
      for (int fm = 0; fm < 2; ++fm) {
        int row = wr * 32 + fm * 16 + rr;
        ah[fm] = ldfrag(As[0], row, kq);
        al[fm] = ldfrag(As[1], row, kq);
      }
#pragma unroll
      for (int fn = 0; fn < 2; ++fn) {
        int nrow = wc * 32 + fn * 16 + rr;
        bh[fn] = ldfrag(Bs[0], nrow, kq);
        bl[fn] = ldfrag(Bs[1], nrow, kq);
      }
#pragma unroll
      for (int fm = 0; fm < 2; ++fm)
#pragma unroll
        for (int fn = 0; fn < 2; ++fn) {
          f32x4 c = acc[p][fm][fn];
          c = __builtin_amdgcn_mfma_f32_16x16x32_bf16(ah[fm], bh[fn], c, 0, 0, 0);
          c = __builtin_amdgcn_mfma_f32_16x16x32_bf16(ah[fm], bl[fn], c, 0, 0, 0);
          c = __builtin_amdgcn_mfma_f32_16x16x32_bf16(al[fm], bh[fn], c, 0, 0, 0);
          acc[p][fm][fn] = c;
        }
    }
  }

  // epilogue: C/D layout col=lane&15, row=(lane>>4)*4+reg (m89-verified)
  float g = 0.f;
  if constexpr (EPI >= 1) g = 1.f / (1.f + __expf(-resw[0]));
#pragma unroll
  for (int fm = 0; fm < 2; ++fm)
#pragma unroll
    for (int fn = 0; fn < 2; ++fn) {
      int cc = col0 + wc * 32 + fn * 16 + rr;
#pragma unroll
      for (int i = 0; i < 4; ++i) {
        int r = row0 + wr * 32 + fm * 16 + kq * 4 + i;
        if (r < M) {
          if constexpr (EPI == 0) {
            outp[(size_t)r * KD + cc] = acc[0][fm][fn][i];
          } else if constexpr (EPI == 1) {
            float o = g * acc[0][fm][fn][i] + (1.f - g) * (acc[1][fm][fn][i] + bres[cc]);
            outp[(size_t)r * KD + cc] = o;
          } else {
            int head = cc >> 5;
            float wwv = wwp[(size_t)r * KH + head];
            float wcv = wcp[(size_t)r * KH + head];
            float o = g * (wwv * acc[0][fm][fn][i] + wcv * acc[1][fm][fn][i])
                    + (1.f - g) * (acc[2][fm][fn][i] + bres[cc]);
            outp[(size_t)r * KD + cc] = o;
          }
        }
      }
    }
}

// weights W[K][256] f32 -> transposed hi/lo bf16 planes [256][K]
__global__ void k_prepB(const float* __restrict__ W, int Kd,
                        ushort* __restrict__ Bh, ushort* __restrict__ Bl) {
  int idx = blockIdx.x * 256 + threadIdx.x;
  if (idx >= Kd * 256) return;
  int n = idx / Kd, k = idx - n * Kd;
  float v = W[(size_t)k * 256 + n];
  ushort h = f2b(v);
  Bh[idx] = h;
  Bl[idx] = f2b(v - b2f(h));
}

// per-node attention dots
__global__ void k_node_dots(
    const float* __restrict__ f, int N,
    const float* __restrict__ a0, float* __restrict__ o0,
    const float* __restrict__ a1, float* __restrict__ o1,
    const float* __restrict__ a2, float* __restrict__ o2)
{
  int idx = blockIdx.x * blockDim.x + threadIdx.x;
  if (idx >= N * KH) return;
  int n = idx >> 3, k = idx & 7;
  const float* fr = f + (size_t)n * KD + k * DH;
  float d0 = 0.f, d1 = 0.f, d2 = 0.f;
#pragma unroll
  for (int i = 0; i < DH; i += 4) {
    float4 fv = *reinterpret_cast<const float4*>(fr + i);
    if (a0) {
      float4 v = *reinterpret_cast<const float4*>(a0 + k * 64 + i);
      d0 += fv.x * v.x + fv.y * v.y + fv.z * v.z + fv.w * v.w;
    }
    if (a1) {
      float4 v = *reinterpret_cast<const float4*>(a1 + k * 64 + i);
      d1 += fv.x * v.x + fv.y * v.y + fv.z * v.z + fv.w * v.w;
    }
    if (a2) {
      float4 v = *reinterpret_cast<const float4*>(a2 + k * 64 + i);
      d2 += fv.x * v.x + fv.y * v.y + fv.z * v.z + fv.w * v.w;
    }
  }
  if (o0) o0[idx] = d0;
  if (o1) o1[idx] = d1;
  if (o2) o2[idx] = d2;
}

// ---------------- CSR build ----------------
__global__ void k_hist(const int* __restrict__ dst, int E, int* __restrict__ cnt) {
  int e = blockIdx.x * 256 + threadIdx.x;
  if (e < E) atomicAdd(&cnt[dst[e]], 1);
}

__global__ void k_scan1(const int* __restrict__ cnt, int n,
                        int* __restrict__ off, int* __restrict__ bsum) {
  __shared__ int sm[256];
  int t = threadIdx.x;
  int i = blockIdx.x * 256 + t;
  int v = (i < n) ? cnt[i] : 0;
  sm[t] = v; __syncthreads();
  for (int o = 1; o < 256; o <<= 1) {
    int x = (t >= o) ? sm[t - o] : 0;
    __syncthreads();
    sm[t] += x;
    __syncthreads();
  }
  if (i < n) off[i] = sm[t] - v;
  if (t == 255) bsum[blockIdx.x] = sm[255];
}

__global__ void k_scan2(int* __restrict__ bsum, int nb) {
  __shared__ int sm[512];
  int t = threadIdx.x;
  int v = (t < nb) ? bsum[t] : 0;
  sm[t] = v; __syncthreads();
  for (int o = 1; o < 512; o <<= 1) {
    int x = (t >= o) ? sm[t - o] : 0;
    __syncthreads();
    sm[t] += x;
    __syncthreads();
  }
  if (t < nb) bsum[t] = sm[t] - v;
}

__global__ void k_scan3(int* __restrict__ off, int n, const int* __restrict__ bsum) {
  int i = blockIdx.x * 256 + threadIdx.x;
  if (i < n) off[i] += bsum[blockIdx.x];
}

__global__ void k_scatter(const int* __restrict__ dst, int E,
                          const int* __restrict__ off, int* __restrict__ cur,
                          int* __restrict__ eidx) {
  int e = blockIdx.x * 256 + threadIdx.x;
  if (e >= E) return;
  int d = dst[e];
  int p = atomicAdd(&cur[d], 1);
  eidx[off[d] + p] = e;
}

// ---------------- dst-centric fused attention + aggregation ----------------
__global__ __launch_bounds__(256) void k_agg_dst(
    const int* __restrict__ eidx, const int* __restrict__ off_,
    const int* __restrict__ cnt_, const int* __restrict__ src,
    const float* __restrict__ el, const float* __restrict__ er,
    const float* __restrict__ fs, float* __restrict__ outp)
{
  __shared__ int ssi[256];
  int d = blockIdx.x;
  int t = threadIdx.x;
  int k = t >> 5;
  int c = cnt_[d];
  float acc = 0.f;
  float s = 0.f;
  if (c > 0) {
    int base = off_[d];
    float erk = er[(size_t)d * KH + k];
    for (int j0 = 0; j0 < c; j0 += 256) {
      int m = min(256, c - j0);
      __syncthreads();
      if (t < m) ssi[t] = src[eidx[base + j0 + t]];
      __syncthreads();
      for (int j = 0; j < m; ++j) {
        int si = ssi[j];
        float a = __expf(leakyf(el[(size_t)si * KH + k] + erk));
        s += a;
        acc = fmaf(fs[(size_t)si * KD + t], a, acc);
      }
    }
    acc = fmaxf(acc / s, 0.f);
  }
  outp[(size_t)d * KD + t] = acc;
}

// tiny pre-contractions
__global__ void k_weff(
    const float* __restrict__ Wmnp, const float* __restrict__ Wrw,
    const float* __restrict__ Wrc, const float* __restrict__ attn,
    float* __restrict__ enp, float* __restrict__ ew, float* __restrict__ ec)
{
  int idx = blockIdx.x * blockDim.x + threadIdx.x;
  if (idx < DIN * KH) {
    int c = idx >> 3, k = idx & 7;
    float sum = 0.f;
    for (int d = 0; d < DH; ++d) sum += Wmnp[(size_t)c * KD + k * DH + d] * attn[k * 64 + d];
    enp[idx] = sum;
  } else if (idx < DIN * KH + KD * KH) {
    int j = idx - DIN * KH;
    int c = j >> 3, k = j & 7;
    float sum = 0.f;
    for (int d = 0; d < DH; ++d) sum += Wrw[(size_t)c * KD + k * DH + d] * attn[k * 64 + 32 + d];
    ew[j] = sum;
  } else if (idx < DIN * KH + 2 * KD * KH) {
    int j = idx - DIN * KH - KD * KH;
    int c = j >> 3, k = j & 7;
    float sum = 0.f;
    for (int d = 0; d < DH; ++d) sum += Wrc[(size_t)c * KD + k * DH + d] * attn[k * 64 + 32 + d];
    ec[j] = sum;
  }
}

// skinny GEMM: out[M,8] = op(A[M,Kdim]) @ W[Kdim,8]
template<bool RELU>
__global__ __launch_bounds__(256) void k_skinny(
    const float* __restrict__ A, int M, int Kdim,
    const float* __restrict__ W, float* __restrict__ outp)
{
  __shared__ float Ws[KD * KH];
  int tid = threadIdx.x;
  for (int i = tid; i < Kdim * KH; i += 256) Ws[i] = W[i];
  __syncthreads();
  int r = blockIdx.x * 32 + (tid >> 3);
  int k = tid & 7;
  if (r >= M) return;
  const float* Ar = A + (size_t)r * Kdim;
  float acc = 0.f;
  for (int c = 0; c < Kdim; c += 4) {
    float4 av = *reinterpret_cast<const float4*>(Ar + c);
    if (RELU) {
      av.x = fmaxf(av.x, 0.f); av.y = fmaxf(av.y, 0.f);
      av.z = fmaxf(av.z, 0.f); av.w = fmaxf(av.w, 0.f);
    }
    acc += av.x * Ws[(c + 0) * KH + k] + av.y * Ws[(c + 1) * KH + k]
         + av.z * Ws[(c + 2) * KH + k] + av.w * Ws[(c + 3) * KH + k];
  }
  outp[(size_t)r * KH + k] = acc;
}

// macro softmax weights over 2 relations
__global__ void k_weights(
    const float* __restrict__ npdot, const float* __restrict__ scw,
    const float* __restrict__ scc, float* __restrict__ ww,
    float* __restrict__ wc, int N8)
{
  int idx = blockIdx.x * blockDim.x + threadIdx.x;
  if (idx >= N8) return;
  float nd = npdot[idx];
  float lw = leakyf(nd + scw[idx]);
  float lc = leakyf(nd + scc[idx]);
  float m = fmaxf(lw, lc);
  float e1 = __expf(lw - m), e2 = __expf(lc - m);
  float inv = 1.f / (e1 + e2);
  ww[idx] = e1 * inv;
  wc[idx] = e2 * inv;
}

static inline void run_relation(hipStream_t stream,
                                const int* src, const int* dst, int E, int n_dst,
                                int* cnt, int* cur, int* off, int* bsum, int* eidx,
                                const float* el, const float* er,
                                const float* fs, float* outp) {
  hipMemsetAsync(cnt, 0, (size_t)n_dst * sizeof(int), stream);
  hipMemsetAsync(cur, 0, (size_t)n_dst * sizeof(int), stream);
  int nb = (n_dst + 255) / 256;
  k_hist<<<(E + 255) / 256, 256, 0, stream>>>(dst, E, cnt);
  k_scan1<<<nb, 256, 0, stream>>>(cnt, n_dst, off, bsum);
  k_scan2<<<1, 512, 0, stream>>>(bsum, nb);
  k_scan3<<<nb, 256, 0, stream>>>(off, n_dst, bsum);
  k_scatter<<<(E + 255) / 256, 256, 0, stream>>>(dst, E, off, cur, eidx);
  k_agg_dst<<<n_dst, 256, 0, stream>>>(eidx, off, cnt, src, el, er, fs, outp);
}

extern "C" void kernel_launch(void* const* d_in, const int* in_sizes, int n_in,
                              void* d_out, int out_size, void* d_ws, size_t ws_size,
                              hipStream_t stream)
{
  const float* feat_a  = (const float*)d_in[0];
  const float* feat_p  = (const float*)d_in[1];
  const float* W_mic_a = (const float*)d_in[2];
  const float* W_mic_p = (const float*)d_in[3];
  const float* attn_a  = (const float*)d_in[4];
  const float* attn_p  = (const float*)d_in[5];
  const float* W_mnp   = (const float*)d_in[7];
  const float* W_rw    = (const float*)d_in[8];
  const float* W_rwb   = (const float*)d_in[9];
  const float* W_rc    = (const float*)d_in[10];
  const float* attn_m  = (const float*)d_in[11];
  const float* W_res_a = (const float*)d_in[12];
  const float* b_res_a = (const float*)d_in[13];
  const float* W_res_p = (const float*)d_in[14];
  const float* b_res_p = (const float*)d_in[15];
  const float* rw_a    = (const float*)d_in[16];
  const float* rw_p    = (const float*)d_in[17];
  const int* w_src  = (const int*)d_in[18];
  const int* w_dst  = (const int*)d_in[19];
  const int* wbsrc  = (const int*)d_in[20];
  const int* wbdst  = (const int*)d_in[21];
  const int* c_src  = (const int*)d_in[22];
  const int* c_dst  = (const int*)d_in[23];
  const int Ew = in_sizes[18], Ewb = in_sizes[20], Ec = in_sizes[22];

  float* ws = (float*)d_ws;
  const size_t SA = (size_t)NAU * KD;      // 12.8M
  const size_t SP = (size_t)NPA * KD;      // 25.6M
  float* fa    = ws;                       // SA
  float* fp    = fa + SA;                  // SP
  float* r_w   = fp + SP;                  // SP
  float* r_wb  = r_w + SP;                 // SA
  float* r_c   = r_wb + SA;                // SP
  float* elA   = r_c + SP;
  float* erA   = elA + (size_t)NAU * KH;
  float* elP   = erA + (size_t)NAU * KH;
  float* erPa  = elP + (size_t)NPA * KH;
  float* erPp  = erPa + (size_t)NPA * KH;
  float* npdot = erPp + (size_t)NPA * KH;
  float* scw   = npdot + (size_t)NPA * KH;
  float* scc   = scw + (size_t)NPA * KH;
  float* wwb   = scc + (size_t)NPA * KH;
  float* wcb   = wwb + (size_t)NPA * KH;
  float* effnp = wcb + (size_t)NPA * KH;   // 128*8
  float* effw  = effnp + DIN * KH;         // 256*8
  float* effc  = effw + KD * KH;           // 256*8
  // bf16 transposed weight planes (ushort), 16B-aligned region
  ushort* bt = (ushort*)(effc + KD * KH);
  ushort* BTmicA_h = bt;                  bt += 256 * DIN;
  ushort* BTmicA_l = bt;                  bt += 256 * DIN;
  ushort* BTmicP_h = bt;                  bt += 256 * DIN;
  ushort* BTmicP_l = bt;                  bt += 256 * DIN;
  ushort* BTrwb_h  = bt;                  bt += 256 * KD;
  ushort* BTrwb_l  = bt;                  bt += 256 * KD;
  ushort* BTrw_h   = bt;                  bt += 256 * KD;
  ushort* BTrw_l   = bt;                  bt += 256 * KD;
  ushort* BTrc_h   = bt;                  bt += 256 * KD;
  ushort* BTrc_l   = bt;                  bt += 256 * KD;
  ushort* BTresA_h = bt;                  bt += 256 * DIN;
  ushort* BTresA_l = bt;                  bt += 256 * DIN;
  ushort* BTresP_h = bt;                  bt += 256 * DIN;
  ushort* BTresP_l = bt;                  bt += 256 * DIN;
  int*   cnt   = (int*)bt;
  int*   cur   = cnt + NPA;
  int*   off   = cur + NPA;
  int*   bsum  = off + NPA;                // 512
  int*   eidx  = bsum + 512;               // up to 1M

  float* out_a = (float*)d_out;
  float* out_p = (float*)d_out + SA;

  // weight prep (transpose + hi/lo split)
  k_prepB<<<DIN, 256, 0, stream>>>(W_mic_a, DIN, BTmicA_h, BTmicA_l);
  k_prepB<<<DIN, 256, 0, stream>>>(W_mic_p, DIN, BTmicP_h, BTmicP_l);
  k_prepB<<<KD,  256, 0, stream>>>(W_rwb,  KD,  BTrwb_h,  BTrwb_l);
  k_prepB<<<KD,  256, 0, stream>>>(W_rw,   KD,  BTrw_h,   BTrw_l);
  k_prepB<<<KD,  256, 0, stream>>>(W_rc,   KD,  BTrc_h,   BTrc_l);
  k_prepB<<<DIN, 256, 0, stream>>>(W_res_a, DIN, BTresA_h, BTresA_l);
  k_prepB<<<DIN, 256, 0, stream>>>(W_res_p, DIN, BTresP_h, BTresP_l);

  // micro projections (MFMA)
  {
    dim3 g((NAU + 63) / 64, 4);
    k_mfma<1, 0><<<g, 256, 0, stream>>>(
        feat_a, DIN, BTmicA_h, BTmicA_l,
        nullptr, 0, nullptr, nullptr, nullptr, 0, nullptr, nullptr,
        NAU, nullptr, nullptr, nullptr, nullptr, fa);
  }
  {
    dim3 g((NPA + 63) / 64, 4);
    k_mfma<1, 0><<<g, 256, 0, stream>>>(
        feat_p, DIN, BTmicP_h, BTmicP_l,
        nullptr, 0, nullptr, nullptr, nullptr, 0, nullptr, nullptr,
        NPA, nullptr, nullptr, nullptr, nullptr, fp);
  }

  // node attention dots
  k_node_dots<<<(NAU * KH + 255) / 256, 256, 0, stream>>>(
      fa, NAU, attn_a, elA, attn_p + 32, erA, nullptr, nullptr);
  k_node_dots<<<(NPA * KH + 255) / 256, 256, 0, stream>>>(
      fp, NPA, attn_p, elP, attn_a + 32, erPa, attn_p + 32, erPp);

  // relations: CSR build + dst-centric fused aggregation (atomic-free)
  run_relation(stream, w_src, w_dst, Ew, NPA, cnt, cur, off, bsum, eidx,
               elA, erPa, fa, r_w);
  run_relation(stream, wbsrc, wbdst, Ewb, NAU, cnt, cur, off, bsum, eidx,
               elP, erA, fp, r_wb);
  run_relation(stream, c_src, c_dst, Ec, NPA, cnt, cur, off, bsum, eidx,
               elP, erPp, fp, r_c);

  // out_a: fused rel+residual (MFMA)
  {
    dim3 g((NAU + 63) / 64, 4);
    k_mfma<2, 1><<<g, 256, 0, stream>>>(
        r_wb, KD, BTrwb_h, BTrwb_l,
        feat_a, DIN, BTresA_h, BTresA_l,
        nullptr, 0, nullptr, nullptr,
        NAU, b_res_a, rw_a, nullptr, nullptr, out_a);
  }

  // macro attention: pre-contract, skinny score GEMMs, softmax weights
  k_weff<<<20, 256, 0, stream>>>(W_mnp, W_rw, W_rc, attn_m, effnp, effw, effc);
  k_skinny<false><<<(NPA + 31) / 32, 256, 0, stream>>>(feat_p, NPA, DIN, effnp, npdot);
  k_skinny<true ><<<(NPA + 31) / 32, 256, 0, stream>>>(r_w, NPA, KD, effw, scw);
  k_skinny<true ><<<(NPA + 31) / 32, 256, 0, stream>>>(r_c, NPA, KD, effc, scc);
  k_weights<<<(NPA * KH + 255) / 256, 256, 0, stream>>>(npdot, scw, scc, wwb, wcb, NPA * KH);

  // out_p: fused triple GEMM with macro weights + residual (MFMA)
  {
    dim3 g((NPA + 63) / 64, 4);
    k_mfma<3, 2><<<g, 256, 0, stream>>>(
        r_w, KD, BTrw_h, BTrw_l,
        r_c, KD, BTrc_h, BTrc_l,
        feat_p, DIN, BTresP_h, BTresP_l,
        NPA, b_res_p, rw_p, wwb, wcb, out_p);
  }
}